// Round 3
// 95.070 us; speedup vs baseline: 1.0595x; 1.0595x over previous
//
#include <hip/hip_runtime.h>

#define NUM_CLASSES 32
#define NBINS (NUM_CLASSES * NUM_CLASSES)   // 1024
#define BLOCK 256
#define GRID1 1024                          // 4 blocks/CU -> 16 waves/CU; ws = 4 MB
#define GRID2 NUM_CLASSES                   // one block per output row

// Stage 1: per-block private LDS histogram, flushed to ws (no global atomics).
// Counts ALL pixels unconditionally (bin = yt*32+yp is always in [0,1024));
// the yt==0 mask is applied in stage 2 by zeroing row 0 (reference: w=0 there).
__global__ __launch_bounds__(BLOCK) void confmat_partial(
    const int* __restrict__ y_true,
    const int* __restrict__ y_pred,
    unsigned int* __restrict__ ws,   // GRID1 x NBINS partial histograms
    int n)
{
    __shared__ __align__(16) unsigned int hist[NBINS];
    // 256 threads x uint4 = 1024 bins zeroed in one store each.
    ((uint4*)hist)[threadIdx.x] = make_uint4(0u, 0u, 0u, 0u);
    __syncthreads();

    const int tid    = blockIdx.x * BLOCK + threadIdx.x;
    const int stride = GRID1 * BLOCK;
    const int n4 = n >> 2;
    const int4* __restrict__ t4 = (const int4*)y_true;
    const int4* __restrict__ p4 = (const int4*)y_pred;

    int i = tid;
    // 8 independent int4 loads in flight before any LDS op. For n = 8M this
    // loop runs exactly twice (32 elems/thread).
    for (; i + 3 * stride < n4; i += 4 * stride) {
        int4 a0 = t4[i];              int4 b0 = p4[i];
        int4 a1 = t4[i + stride];     int4 b1 = p4[i + stride];
        int4 a2 = t4[i + 2 * stride]; int4 b2 = p4[i + 2 * stride];
        int4 a3 = t4[i + 3 * stride]; int4 b3 = p4[i + 3 * stride];
        atomicAdd(&hist[(a0.x << 5) | b0.x], 1u);
        atomicAdd(&hist[(a0.y << 5) | b0.y], 1u);
        atomicAdd(&hist[(a0.z << 5) | b0.z], 1u);
        atomicAdd(&hist[(a0.w << 5) | b0.w], 1u);
        atomicAdd(&hist[(a1.x << 5) | b1.x], 1u);
        atomicAdd(&hist[(a1.y << 5) | b1.y], 1u);
        atomicAdd(&hist[(a1.z << 5) | b1.z], 1u);
        atomicAdd(&hist[(a1.w << 5) | b1.w], 1u);
        atomicAdd(&hist[(a2.x << 5) | b2.x], 1u);
        atomicAdd(&hist[(a2.y << 5) | b2.y], 1u);
        atomicAdd(&hist[(a2.z << 5) | b2.z], 1u);
        atomicAdd(&hist[(a2.w << 5) | b2.w], 1u);
        atomicAdd(&hist[(a3.x << 5) | b3.x], 1u);
        atomicAdd(&hist[(a3.y << 5) | b3.y], 1u);
        atomicAdd(&hist[(a3.z << 5) | b3.z], 1u);
        atomicAdd(&hist[(a3.w << 5) | b3.w], 1u);
    }
    for (; i < n4; i += stride) {
        int4 a = t4[i]; int4 b = p4[i];
        atomicAdd(&hist[(a.x << 5) | b.x], 1u);
        atomicAdd(&hist[(a.y << 5) | b.y], 1u);
        atomicAdd(&hist[(a.z << 5) | b.z], 1u);
        atomicAdd(&hist[(a.w << 5) | b.w], 1u);
    }
    // Scalar tail (n not divisible by 4).
    for (int j = (n4 << 2) + tid; j < n; j += stride) {
        atomicAdd(&hist[(y_true[j] << 5) | y_pred[j]], 1u);
    }

    __syncthreads();

    // Flush: plain coalesced uint4 stores, 4 KB per block, no atomics.
    uint4* __restrict__ w4 = (uint4*)(ws + (size_t)blockIdx.x * NBINS);
    const uint4* __restrict__ h4 = (const uint4*)hist;
    w4[threadIdx.x] = h4[threadIdx.x];
}

// Stage 2: block b sums row b (32 bins) across all GRID1 partials and writes
// it with plain stores. Block 0 writes zeros (the yt==0 mask). No memset, no
// global atomics anywhere.
__global__ __launch_bounds__(BLOCK) void confmat_reduce(
    const unsigned int* __restrict__ ws,
    float* __restrict__ out)
{
    __shared__ unsigned int sums[NUM_CLASSES];
    if (threadIdx.x < NUM_CLASSES) sums[threadIdx.x] = 0u;
    __syncthreads();

    // Thread t: q = uint4-column within the row (8 per row), c = partial-chunk.
    const int q = threadIdx.x & 7;            // 0..7  (4 bins each)
    const int c = threadIdx.x >> 3;           // 0..31 (chunk of partials)
    const int row4 = blockIdx.x * (NUM_CLASSES / 4);  // uint4 index of row start
    const uint4* __restrict__ w4 = (const uint4*)ws;

    unsigned int sx = 0, sy = 0, sz = 0, sw = 0;
    const int chunk = GRID1 / 32;             // 32 partials per chunk
    #pragma unroll 8
    for (int k = 0; k < chunk; ++k) {
        int p = c * chunk + k;
        uint4 v = w4[(size_t)p * (NBINS / 4) + row4 + q];
        sx += v.x; sy += v.y; sz += v.z; sw += v.w;
    }
    atomicAdd(&sums[q * 4 + 0], sx);
    atomicAdd(&sums[q * 4 + 1], sy);
    atomicAdd(&sums[q * 4 + 2], sz);
    atomicAdd(&sums[q * 4 + 3], sw);
    __syncthreads();

    if (threadIdx.x < NUM_CLASSES) {
        float v = (blockIdx.x == 0) ? 0.0f : (float)sums[threadIdx.x];
        out[blockIdx.x * NUM_CLASSES + threadIdx.x] = v;
    }
}

extern "C" void kernel_launch(void* const* d_in, const int* in_sizes, int n_in,
                              void* d_out, int out_size, void* d_ws, size_t ws_size,
                              hipStream_t stream) {
    const int* y_true = (const int*)d_in[0];
    const int* y_pred = (const int*)d_in[1];
    float* out = (float*)d_out;
    unsigned int* ws = (unsigned int*)d_ws;    // needs GRID1*NBINS*4 = 4 MB
    int n = in_sizes[0];

    confmat_partial<<<GRID1, BLOCK, 0, stream>>>(y_true, y_pred, ws, n);
    confmat_reduce<<<GRID2, BLOCK, 0, stream>>>(ws, out);
}